// Round 17
// baseline (1329.479 us; speedup 1.0000x reference)
//
#include <hip/hip_runtime.h>
#include <hip/hip_bf16.h>

#define BB 8
#define CH 256
#define C8 32
#define NP 4096   // 64*64

typedef __attribute__((ext_vector_type(8))) short bf16x8;
typedef __attribute__((ext_vector_type(4))) float f32x4;

#define MFMA16(a, b, c) __builtin_amdgcn_mfma_f32_16x16x32_bf16(a, b, c, 0, 0, 0)
#define SBAR() __builtin_amdgcn_sched_barrier(0)

#if __has_builtin(__builtin_amdgcn_exp2f)
#define EXP2(x) __builtin_amdgcn_exp2f(x)
#else
#define EXP2(x) exp2f(x)
#endif

#define LOG2E 1.44269504088896340736f

__device__ __forceinline__ void async_copy16(const void* src, void* dst_lds) {
    __builtin_amdgcn_global_load_lds(
        (const __attribute__((address_space(1))) unsigned int*)src,
        (__attribute__((address_space(3))) unsigned int*)dst_lds, 16, 0, 0);
}

__device__ __forceinline__ unsigned long long pack4bf(float a, float b, float c, float d) {
    union { __hip_bfloat16 h[4]; unsigned long long u; } p;
    p.h[0] = __float2bfloat16(a);
    p.h[1] = __float2bfloat16(b);
    p.h[2] = __float2bfloat16(c);
    p.h[3] = __float2bfloat16(d);
    return p.u;
}

// Stage a [nrows][64] bf16 LDS panel (128B rows, XOR-swizzled: data k-chunk t
// of row r lives at slot t^(r&7)) from row-major bf16 global. 256-thread form.
__device__ __forceinline__ void stage_panel64(
    const __hip_bfloat16* __restrict__ src, int rowStride, int k0,
    __hip_bfloat16* lds, int nrows, int w, int l)
{
    const int nslots = nrows * 8;
    for (int S0 = w*64; S0 < nslots; S0 += 256) {
        int S = S0 + l;
        int r = S >> 3, s = S & 7;
        int jb = s ^ (r & 7);
        async_copy16(src + (size_t)r*rowStride + k0 + jb*8,
                     (char*)lds + (size_t)S0*16);
    }
}

__device__ __forceinline__ bf16x8 frag64(const __hip_bfloat16* lds, int r, int t) {
    return *(const bf16x8*)((const char*)lds + r*128 + ((t ^ (r & 7)) << 4));
}

// ------- K0: x -> xbT [B][N][C] bf16 + xb [B][C][N] bf16 (+ weights) --------
__global__ __launch_bounds__(256) void convert_T(
    const float* __restrict__ x, __hip_bfloat16* __restrict__ xbT,
    __hip_bfloat16* __restrict__ xb,
    const float* __restrict__ wq, const float* __restrict__ wk,
    const float* __restrict__ wv,
    __hip_bfloat16* __restrict__ wqkb, __hip_bfloat16* __restrict__ wvb,
    const float* __restrict__ gamma)
{
    int b = blockIdx.z, c0 = blockIdx.y * 64, n0 = blockIdx.x * 64;
    __shared__ float t[64][65];
    int tid = threadIdx.x;
    const bool do_cam = (gamma[0] != 0.0f);

    if (b == 0) {
        int wid = blockIdx.y * 64 + blockIdx.x;
        #pragma unroll
        for (int e = 0; e < 2; ++e) {
            int id = wid*320 + e*256 + tid;
            if (e*256 + tid < 320) {
                if (id < 64*256) {
                    float v = (id < 32*256) ? wq[id] : wk[id - 32*256];
                    wqkb[id] = __float2bfloat16(v);
                } else {
                    int j = id - 64*256;
                    wvb[j] = __float2bfloat16(wv[j]);
                }
            }
        }
    }

    int nn = tid & 63, ch = tid >> 6;
    const float* xp = x + (size_t)b*CH*NP + (size_t)c0*NP + n0;
    #pragma unroll
    for (int u = 0; u < 16; ++u) {
        float v = xp[(size_t)(ch + u*4)*NP + nn];
        t[ch + u*4][nn] = v;
        if (do_cam)
            xb[((size_t)b*CH + c0 + ch + u*4)*NP + n0 + nn] = __float2bfloat16(v);
    }
    __syncthreads();
    int n = tid >> 2, seg = tid & 3;
    union { __hip_bfloat16 h[16]; bf16x8 v[2]; } u16;
    #pragma unroll
    for (int u = 0; u < 16; ++u)
        u16.h[u] = __float2bfloat16(t[seg*16 + u][n]);
    __hip_bfloat16* dst = xbT + ((size_t)b*NP + n0 + n)*CH + c0 + seg*16;
    *(bf16x8*)dst = u16.v[0];
    *(bf16x8*)(dst + 8) = u16.v[1];
}

// ---- K1 (fused): qk (x<32) | v (32<=x<96) | energy (96<=x<112) -------------
__global__ __launch_bounds__(256) void mid_kernel(
    const __hip_bfloat16* __restrict__ xbT, const __hip_bfloat16* __restrict__ xb,
    const __hip_bfloat16* __restrict__ wqkb, const __hip_bfloat16* __restrict__ wvb,
    const float* __restrict__ bq, const float* __restrict__ bk,
    const float* __restrict__ bv,
    __hip_bfloat16* __restrict__ qt, __hip_bfloat16* __restrict__ kt,
    __hip_bfloat16* __restrict__ vb, float* __restrict__ E_part,
    const float* __restrict__ gamma)
{
    const int xrole = blockIdx.x, b = blockIdx.y;
    const int tid = threadIdx.x;
    const int w = tid >> 6, l = tid & 63, g = l >> 4, li = l & 15;

    __shared__ __align__(16) char smem[40960];

    if (xrole < 32) {
        const int n0 = xrole * 128;
        __hip_bfloat16* Ap = (__hip_bfloat16*)smem;
        __hip_bfloat16* Bp = (__hip_bfloat16*)(smem + 16384);

        f32x4 acc[2][4];
        #pragma unroll
        for (int mf = 0; mf < 2; ++mf)
            #pragma unroll
            for (int nf = 0; nf < 4; ++nf) acc[mf][nf] = (f32x4){0.f,0.f,0.f,0.f};

        const __hip_bfloat16* asrc = xbT + ((size_t)b*NP + n0)*CH;
        for (int kt4 = 0; kt4 < 4; ++kt4) {
            stage_panel64(asrc, CH, kt4*64, Ap, 128, w, l);
            stage_panel64(wqkb, CH, kt4*64, Bp, 64, w, l);
            __syncthreads();
            #pragma unroll
            for (int ks = 0; ks < 2; ++ks) {
                bf16x8 af[2], bf[4];
                #pragma unroll
                for (int mf = 0; mf < 2; ++mf) af[mf] = frag64(Ap, w*32 + mf*16 + li, ks*4 + g);
                #pragma unroll
                for (int nf = 0; nf < 4; ++nf) bf[nf] = frag64(Bp, nf*16 + li, ks*4 + g);
                #pragma unroll
                for (int mf = 0; mf < 2; ++mf)
                    #pragma unroll
                    for (int nf = 0; nf < 4; ++nf)
                        acc[mf][nf] = MFMA16(af[mf], bf[nf], acc[mf][nf]);
            }
            __syncthreads();
        }
        #pragma unroll
        for (int mf = 0; mf < 2; ++mf)
            #pragma unroll
            for (int nf = 0; nf < 4; ++nf)
                #pragma unroll
                for (int q = 0; q < 4; ++q) {
                    int n = n0 + w*32 + mf*16 + g*4 + q;
                    int o = nf*16 + li;
                    float bias = (o < 32) ? bq[o] : bk[o - 32];
                    float scl  = (o < 32) ? LOG2E : 1.0f;
                    __hip_bfloat16* dst = (o < 32) ? qt : kt;
                    dst[((size_t)b*NP + n)*C8 + (o & 31)] =
                        __float2bfloat16((acc[mf][nf][q] + bias) * scl);
                }
    } else if (xrole < 96) {
        const int n0 = (xrole - 32) * 64;
        __hip_bfloat16* Ap = (__hip_bfloat16*)smem;
        __hip_bfloat16* Bp = (__hip_bfloat16*)(smem + 32768);
        __hip_bfloat16* vt = (__hip_bfloat16*)smem;

        f32x4 acc[4][4];
        #pragma unroll
        for (int mf = 0; mf < 4; ++mf)
            #pragma unroll
            for (int nf = 0; nf < 4; ++nf) acc[mf][nf] = (f32x4){0.f,0.f,0.f,0.f};

        const __hip_bfloat16* bsrc = xbT + ((size_t)b*NP + n0)*CH;
        for (int kt4 = 0; kt4 < 4; ++kt4) {
            stage_panel64(wvb, CH, kt4*64, Ap, 256, w, l);
            stage_panel64(bsrc, CH, kt4*64, Bp, 64, w, l);
            __syncthreads();
            #pragma unroll
            for (int ks = 0; ks < 2; ++ks) {
                bf16x8 af[4], bf[4];
                #pragma unroll
                for (int mf = 0; mf < 4; ++mf) af[mf] = frag64(Ap, w*64 + mf*16 + li, ks*4 + g);
                #pragma unroll
                for (int nf = 0; nf < 4; ++nf) bf[nf] = frag64(Bp, nf*16 + li, ks*4 + g);
                #pragma unroll
                for (int mf = 0; mf < 4; ++mf)
                    #pragma unroll
                    for (int nf = 0; nf < 4; ++nf)
                        acc[mf][nf] = MFMA16(af[mf], bf[nf], acc[mf][nf]);
            }
            __syncthreads();
        }
        #pragma unroll
        for (int mf = 0; mf < 4; ++mf)
            #pragma unroll
            for (int nf = 0; nf < 4; ++nf)
                #pragma unroll
                for (int q = 0; q < 4; ++q) {
                    int c = w*64 + mf*16 + g*4 + q;
                    int n = nf*16 + li;
                    vt[c*72 + n] = __float2bfloat16(acc[mf][nf][q] + bv[c]);
                }
        __syncthreads();
        for (int S = tid; S < 2048; S += 256) {
            int c = S >> 3, s = S & 7;
            bf16x8 v = *(const bf16x8*)((const char*)vt + c*144 + s*16);
            *(bf16x8*)(vb + ((size_t)b*CH + c)*NP + n0 + s*8) = v;
        }
    } else {
        if (gamma[0] == 0.0f) return;   // CAM contributes gamma*cam == 0
        const int idx = xrole - 96;
        const int rh = idx & 3, kp = idx >> 2;
        __hip_bfloat16* P = (__hip_bfloat16*)smem;

        f32x4 acc[16];
        #pragma unroll
        for (int nf = 0; nf < 16; ++nf) acc[nf] = (f32x4){0.f,0.f,0.f,0.f};

        const __hip_bfloat16* xp = xb + (size_t)b*CH*NP;
        for (int kt4 = 0; kt4 < 16; ++kt4) {
            int k0 = kp*1024 + kt4*64;
            stage_panel64(xp, NP, k0, P, 256, w, l);
            __syncthreads();
            #pragma unroll
            for (int ks = 0; ks < 2; ++ks) {
                bf16x8 af = frag64(P, rh*64 + w*16 + li, ks*4 + g);
                #pragma unroll
                for (int nf = 0; nf < 16; ++nf) {
                    bf16x8 bf = frag64(P, nf*16 + li, ks*4 + g);
                    acc[nf] = MFMA16(af, bf, acc[nf]);
                }
            }
            __syncthreads();
        }
        #pragma unroll
        for (int nf = 0; nf < 16; ++nf)
            #pragma unroll
            for (int q = 0; q < 4; ++q) {
                int r = rh*64 + w*16 + g*4 + q;
                int c = nf*16 + li;
                E_part[(((size_t)b*4 + kp)*CH + r)*CH + c] = acc[nf][q];
            }
    }
}

// -------------------- K4: softmax over C (fused partial reduce) -> bf16 -----
__global__ __launch_bounds__(256) void cam_softmax(
    const float* __restrict__ E_part, __hip_bfloat16* __restrict__ attnb,
    const float* __restrict__ gamma)
{
    if (gamma[0] == 0.0f) return;       // CAM contributes gamma*cam == 0
    int b = blockIdx.y, r = blockIdx.x;
    int tid = threadIdx.x;
    int lane = tid & 63, wid = tid >> 6;
    const float* base = E_part + ((size_t)b*4*CH + r)*CH + tid;
    float e = base[0] + base[CH*CH] + base[2*CH*CH] + base[3*CH*CH];

    __shared__ float redm[4], reds[4];
    float m = e;
    #pragma unroll
    for (int off = 32; off >= 1; off >>= 1) m = fmaxf(m, __shfl_xor(m, off));
    if (lane == 0) redm[wid] = m;
    __syncthreads();
    m = fmaxf(fmaxf(redm[0], redm[1]), fmaxf(redm[2], redm[3]));

    float p = __expf(e - m);
    float s = p;
    #pragma unroll
    for (int off = 32; off >= 1; off >>= 1) s += __shfl_xor(s, off);
    if (lane == 0) reds[wid] = s;
    __syncthreads();
    s = reds[0] + reds[1] + reds[2] + reds[3];
    attnb[((size_t)b*CH + r)*CH + tid] = __float2bfloat16(p / s);
}

// ---- K6: PAM flash v17 — wave-private everything, ZERO loop barriers -------
// wave = (jh = w&1: j-half 32, ch = w>>1: c-half 128). QK duplicated across
// the 2 ch-waves (cheap) so P, V, ps are all wave-private: no s_barrier in
// the loop. vs rows: 128B = channel pair (c,c^1), chunk pos
// p = (4(c&1)+jc) ^ ((c>>1)&7); ps rows: 128B = i pair, same hash — both
// analytically ~2-way bank-free. Pipeline: QK(jt+1) ∥ PV(jt) (v15-proven).
// Post-loop: jh-pair partial (acc,l) combined via one LDS exchange.
__global__ __launch_bounds__(256, 2) void pam_flash(
    const __hip_bfloat16* __restrict__ qg,   // [B][N][32] (pre-scaled)
    const __hip_bfloat16* __restrict__ kg,   // [B][N][32]
    const __hip_bfloat16* __restrict__ vg,   // [B][C][N]
    const __hip_bfloat16* __restrict__ attnb,// [B][C][C]
    const __hip_bfloat16* __restrict__ xbT,  // [B][N][C]
    const float* __restrict__ x,
    const float* __restrict__ gamma,
    float* __restrict__ out)
{
    const int bid = blockIdx.x;
    const int b   = bid & 7;                 // batch -> XCD pin (L2 residency)
    const int i0  = (bid >> 3) * 64;
    const int tid = threadIdx.x;
    const int w   = tid >> 6;
    const int jh  = w & 1;                   // j-half
    const int ch  = w >> 1;                  // c-half
    const int l   = tid & 63;
    const int g   = l >> 4;
    const int li  = l & 15;

    __shared__ __align__(16) char smem[67584];   // vs 32K | ps 2x16K | lshx 2K
    char* vsw = smem + w*8192;                   // wave V region: 64 rows x 128B
    char* psb[2];
    psb[0] = smem + 32768 + w*4096;              // 32 rows x 128B
    psb[1] = smem + 49152 + w*4096;
    float* lshx = (float*)(smem + 65536);        // [4][2][64]

    // ---- V staging (wave-private, DMA-linear): slot s = it*64 + l ----
    // row = s>>3, p = s&7; q8 = p ^ (row&7); c_local = 2row + (q8>>2); jc = q8&3
    const int q8  = (l & 7) ^ ((l >> 3) & 7);
    const int cA  = 2*(l >> 3) + (q8 >> 2);
    const int jcA = q8 & 3;
    const char* vbase = (const char*)vg +
        ((size_t)(b*CH + ch*128 + cA)*NP + jh*32 + jcA*8)*2;

#define ISSUE_V(JT)                                                           \
    { _Pragma("unroll")                                                       \
      for (int it = 0; it < 8; ++it)                                          \
          async_copy16(vbase + (size_t)(JT)*128 + (size_t)it*(16*(size_t)NP*2),\
                       vsw + it*1024); }

    // shared offset pieces
    const int i1   = li & 1;
    const int hsh  = li >> 1;                 // (i>>1)&7 == (c>>1)&7 hash
    const int rowb = hsh * 128;
    const int pvof = ((4*i1 + g) ^ hsh) << 4; // chunk pos for reads (jc = g)

    // ---- Q frags ----
    const char* qbase = (const char*)qg + ((size_t)b*NP + i0)*64;
    bf16x8 qf[4];
    #pragma unroll
    for (int t = 0; t < 4; ++t)
        qf[t] = *(const bf16x8*)(qbase + (t*16 + li)*64 + g*16);

    // ---- K pointers: row j = jt*64 + jh*32 + js*16 + li, chunk g ----
    const char* kptr = (const char*)kg + ((size_t)b*NP + jh*32 + li)*64 + g*16;

    // prologue (order pinned): K(0), V(0) x8, K(1), K(2)
    bf16x8 ka0 = *(const bf16x8*)(kptr);
    bf16x8 ka1 = *(const bf16x8*)(kptr + 1024);
    SBAR();
    ISSUE_V(0);
    SBAR();
    bf16x8 kc0 = *(const bf16x8*)(kptr + 4096);
    bf16x8 kc1 = *(const bf16x8*)(kptr + 4096 + 1024);
    bf16x8 kn0 = *(const bf16x8*)(kptr + 8192);
    bf16x8 kn1 = *(const bf16x8*)(kptr + 8192 + 1024);
    SBAR();

    f32x4 acc[4][8];
    #pragma unroll
    for (int t = 0; t < 4; ++t)
        #pragma unroll
        for (int cf = 0; cf < 8; ++cf)
            acc[t][cf] = (f32x4){0.f, 0.f, 0.f, 0.f};
    float lacc[4] = {0.f, 0.f, 0.f, 0.f};

#define PS_WRITE(PSB, S0, S1)                                                 \
    { _Pragma("unroll")                                                       \
      for (int jtt = 0; jtt < 2; ++jtt)                                       \
          _Pragma("unroll")                                                   \
          for (int t = 0; t < 4; ++t) {                                       \
              f32x4 sv = jtt ? S1[t] : S0[t];                                 \
              float p0 = EXP2(sv[0]);                                         \
              float p1 = EXP2(sv[1]);                                         \
              float p2 = EXP2(sv[2]);                                         \
              float p3 = EXP2(sv[3]);                                         \
              lacc[t] += (p0 + p1) + (p2 + p3);                               \
              int chunk = 4*i1 + jtt*2 + (g >> 1);                            \
              *(unsigned long long*)((PSB) + t*1024 + rowb +                  \
                  (((chunk ^ hsh)) << 4) + ((g & 1) << 3))                    \
                  = pack4bf(p0, p1, p2, p3);                                  \
          } }

#define PV_BLOCK(PSB)                                                         \
    { bf16x8 ap[4];                                                           \
      _Pragma("unroll")                                                       \
      for (int t = 0; t < 4; ++t)                                             \
          ap[t] = *(const bf16x8*)((PSB) + t*1024 + rowb + pvof);             \
      _Pragma("unroll")                                                       \
      for (int cf = 0; cf < 8; ++cf) {                                        \
          bf16x8 bv = *(const bf16x8*)(vsw + cf*1024 + rowb + pvof);          \
          _Pragma("unroll")                                                   \
          for (int t = 0; t < 4; ++t)                                         \
              acc[t][cf] = MFMA16(ap[t], bv, acc[t][cf]);                     \
      } }

    // ---- P(0) -> ps[0] ----
    {
        f32x4 s0[4], s1[4];
        #pragma unroll
        for (int t = 0; t < 4; ++t) {
            f32x4 z = (f32x4){0.f, 0.f, 0.f, 0.f};
            s0[t] = MFMA16(ka0, qf[t], z);
            s1[t] = MFMA16(ka1, qf[t], z);
        }
        PS_WRITE(psb[0], s0, s1);
    }

    // ---- barrier-free pipelined loop: QK(jt+1) ∥ PV(jt) ----
    for (int jt = 0; jt < 63; ++jt) {
        char* psc = psb[jt & 1];
        char* psn = psb[(jt & 1) ^ 1];

        asm volatile("s_waitcnt vmcnt(2)" ::: "memory");   // V(jt) landed
        SBAR();
        __builtin_amdgcn_s_setprio(1);
        f32x4 s0[4], s1[4];
        #pragma unroll
        for (int t = 0; t < 4; ++t) {
            f32x4 z = (f32x4){0.f, 0.f, 0.f, 0.f};
            s0[t] = MFMA16(kc0, qf[t], z);
            s1[t] = MFMA16(kc1, qf[t], z);
        }
        PV_BLOCK(psc);
        __builtin_amdgcn_s_setprio(0);
        PS_WRITE(psn, s0, s1);
        SBAR();
        ISSUE_V(jt + 1);           // after PV reads (program order, same wave)
        SBAR();
        kc0 = kn0; kc1 = kn1;
        {
            int kn3 = (jt + 3 < 64) ? (jt + 3) : 63;
            kn0 = *(const bf16x8*)(kptr + (size_t)kn3*4096);
            kn1 = *(const bf16x8*)(kptr + (size_t)kn3*4096 + 1024);
        }
        SBAR();
    }

    // ---- drain PV(63) ----
    asm volatile("s_waitcnt vmcnt(0)" ::: "memory");
    SBAR();
    PV_BLOCK(psb[1]);

    // ---- combine jh pairs: exchange the i-half each wave does NOT keep ----
    __syncthreads();                       // all waves done with vs/ps
    char* regw = smem + w*16384;
    #pragma unroll
    for (int i2 = 0; i2 < 2; ++i2) {
        int te = (1 - jh)*2 + i2;
        #pragma unroll
        for (int cf = 0; cf < 8; ++cf)
            *(f32x4*)(regw + ((i2*8 + cf)*64 + l)*16) = acc[te][cf];
        lshx[(w*2 + i2)*64 + l] = lacc[te];
    }
    __syncthreads();
    char* regp = smem + (w ^ 1)*16384;
    #pragma unroll
    for (int i2 = 0; i2 < 2; ++i2) {
        int tk = jh*2 + i2;
        #pragma unroll
        for (int cf = 0; cf < 8; ++cf) {
            f32x4 o = *(const f32x4*)(regp + ((i2*8 + cf)*64 + l)*16);
            acc[tk][cf] += o;
        }
        lacc[tk] += lshx[((w ^ 1)*2 + i2)*64 + l];
    }

    // ---- l reduce over lane groups; redistribute per output row ----
    float linv[2][4];
    #pragma unroll
    for (int i2 = 0; i2 < 2; ++i2) {
        int tk = jh*2 + i2;
        float v = lacc[tk];
        v += __shfl_xor(v, 16);
        v += __shfl_xor(v, 32);
        #pragma unroll
        for (int r = 0; r < 4; ++r)
            linv[i2][r] = 1.0f / __shfl(v, (l & 48) | (g*4 + r));
    }

    // ---- CAM epilogue (only when gamma != 0) ----
    const float g0 = gamma[0];
    f32x4 cacc[2][8];
    #pragma unroll
    for (int i2 = 0; i2 < 2; ++i2)
        #pragma unroll
        for (int cf = 0; cf < 8; ++cf)
            cacc[i2][cf] = (f32x4){0.f, 0.f, 0.f, 0.f};

    if (g0 != 0.0f) {
        __syncthreads();                       // region reads complete
        __hip_bfloat16* Bpan = (__hip_bfloat16*)smem;            // 256x64 attn
        __hip_bfloat16* Apan = (__hip_bfloat16*)(smem + 32768);  // 64x64 xbT
        const __hip_bfloat16* csrc = attnb + (size_t)b*CH*CH;
        const __hip_bfloat16* nsrc = xbT + ((size_t)b*NP + i0)*CH;
        for (int kt4 = 0; kt4 < 4; ++kt4) {
            stage_panel64(csrc, CH, kt4*64, Bpan, 256, w, l);
            stage_panel64(nsrc, CH, kt4*64, Apan, 64, w, l);
            __syncthreads();
            #pragma unroll
            for (int ks = 0; ks < 2; ++ks) {
                bf16x8 af2[2], bfv[8];
                #pragma unroll
                for (int i2 = 0; i2 < 2; ++i2)
                    af2[i2] = frag64(Apan, (jh*2 + i2)*16 + li, ks*4 + g);
                #pragma unroll
                for (int cf = 0; cf < 8; ++cf)
                    bfv[cf] = frag64(Bpan, ch*128 + cf*16 + li, ks*4 + g);
                #pragma unroll
                for (int i2 = 0; i2 < 2; ++i2)
                    #pragma unroll
                    for (int cf = 0; cf < 8; ++cf)
                        cacc[i2][cf] = MFMA16(af2[i2], bfv[cf], cacc[i2][cf]);
            }
            __syncthreads();
        }
    }

    // ---- fused write: out = gamma*cam + x + pam/l ----
    #pragma unroll
    for (int i2 = 0; i2 < 2; ++i2) {
        int tk = jh*2 + i2;
        #pragma unroll
        for (int cf = 0; cf < 8; ++cf) {
            int c = ch*128 + cf*16 + li;
            size_t base = ((size_t)b*CH + c)*NP + i0 + tk*16 + g*4;
            float4 xv = *(const float4*)(x + base);
            float4 o;
            o.x = g0*cacc[i2][cf][0] + xv.x + acc[tk][cf][0]*linv[i2][0];
            o.y = g0*cacc[i2][cf][1] + xv.y + acc[tk][cf][1]*linv[i2][1];
            o.z = g0*cacc[i2][cf][2] + xv.z + acc[tk][cf][2]*linv[i2][2];
            o.w = g0*cacc[i2][cf][3] + xv.w + acc[tk][cf][3]*linv[i2][3];
            *(float4*)(out + base) = o;
        }
    }
#undef ISSUE_V
#undef PS_WRITE
#undef PV_BLOCK
}

// ---------------------------------------------------------------------------
extern "C" void kernel_launch(void* const* d_in, const int* in_sizes, int n_in,
                              void* d_out, int out_size, void* d_ws, size_t ws_size,
                              hipStream_t stream)
{
    const float* x     = (const float*)d_in[0];
    const float* gamma = (const float*)d_in[1];
    const float* wq    = (const float*)d_in[2];
    const float* bq    = (const float*)d_in[3];
    const float* wk    = (const float*)d_in[4];
    const float* bk    = (const float*)d_in[5];
    const float* wv    = (const float*)d_in[6];
    const float* bv    = (const float*)d_in[7];
    float* out = (float*)d_out;

    char* ws = (char*)d_ws;
    __hip_bfloat16* xbT   = (__hip_bfloat16*)ws;                 ws += (size_t)BB*NP*CH*2;
    __hip_bfloat16* xb    = (__hip_bfloat16*)ws;                 ws += (size_t)BB*CH*NP*2;
    __hip_bfloat16* qtb   = (__hip_bfloat16*)ws;                 ws += (size_t)BB*NP*C8*2;
    __hip_bfloat16* ktb   = (__hip_bfloat16*)ws;                 ws += (size_t)BB*NP*C8*2;
    __hip_bfloat16* vbb   = (__hip_bfloat16*)ws;                 ws += (size_t)BB*CH*NP*2;
    __hip_bfloat16* wqkb  = (__hip_bfloat16*)ws;                 ws += 64*CH*2;
    __hip_bfloat16* wvb   = (__hip_bfloat16*)ws;                 ws += CH*CH*2;
    float*          Epart = (float*)ws;                          ws += (size_t)BB*4*CH*CH*4;
    __hip_bfloat16* attnb = (__hip_bfloat16*)ws;                 ws += (size_t)BB*CH*CH*2;

    convert_T  <<<dim3(64, 4, BB),  256, 0, stream>>>(x, xbT, xb, wq, wk, wv, wqkb, wvb, gamma);
    mid_kernel <<<dim3(112, BB),    256, 0, stream>>>(xbT, xb, wqkb, wvb, bq, bk, bv,
                                                      qtb, ktb, vbb, Epart, gamma);
    cam_softmax<<<dim3(CH, BB),     256, 0, stream>>>(Epart, attnb, gamma);
    pam_flash  <<<dim3(512),        256, 0, stream>>>(qtb, ktb, vbb, attnb, xbT,
                                                      x, gamma, out);
}

// Round 18
// 123.914 us; speedup vs baseline: 10.7291x; 10.7291x over previous
//
#include <hip/hip_runtime.h>
#include <hip/hip_bf16.h>

#define BB 8
#define CH 256
#define C8 32
#define NP 4096   // 64*64

typedef __attribute__((ext_vector_type(8))) short bf16x8;
typedef __attribute__((ext_vector_type(4))) float f32x4;

#define MFMA16(a, b, c) __builtin_amdgcn_mfma_f32_16x16x32_bf16(a, b, c, 0, 0, 0)
#define SBAR() __builtin_amdgcn_sched_barrier(0)

#if __has_builtin(__builtin_amdgcn_exp2f)
#define EXP2(x) __builtin_amdgcn_exp2f(x)
#else
#define EXP2(x) exp2f(x)
#endif

#define LOG2E 1.44269504088896340736f

__device__ __forceinline__ void async_copy16(const void* src, void* dst_lds) {
    __builtin_amdgcn_global_load_lds(
        (const __attribute__((address_space(1))) unsigned int*)src,
        (__attribute__((address_space(3))) unsigned int*)dst_lds, 16, 0, 0);
}

__device__ __forceinline__ unsigned long long pack4bf(float a, float b, float c, float d) {
    union { __hip_bfloat16 h[4]; unsigned long long u; } p;
    p.h[0] = __float2bfloat16(a);
    p.h[1] = __float2bfloat16(b);
    p.h[2] = __float2bfloat16(c);
    p.h[3] = __float2bfloat16(d);
    return p.u;
}

// Stage a [nrows][64] bf16 LDS panel (128B rows, XOR-swizzled: data k-chunk t
// of row r lives at slot t^(r&7)) from row-major bf16 global. 256-thread form.
__device__ __forceinline__ void stage_panel64(
    const __hip_bfloat16* __restrict__ src, int rowStride, int k0,
    __hip_bfloat16* lds, int nrows, int w, int l)
{
    const int nslots = nrows * 8;
    for (int S0 = w*64; S0 < nslots; S0 += 256) {
        int S = S0 + l;
        int r = S >> 3, s = S & 7;
        int jb = s ^ (r & 7);
        async_copy16(src + (size_t)r*rowStride + k0 + jb*8,
                     (char*)lds + (size_t)S0*16);
    }
}

__device__ __forceinline__ bf16x8 frag64(const __hip_bfloat16* lds, int r, int t) {
    return *(const bf16x8*)((const char*)lds + r*128 + ((t ^ (r & 7)) << 4));
}

// ------- K0: x -> xbT [B][N][C] bf16 + xb [B][C][N] bf16 (+ weights) --------
// xb is only consumed by the CAM energy path; skipped when gamma==0.
__global__ __launch_bounds__(256) void convert_T(
    const float* __restrict__ x, __hip_bfloat16* __restrict__ xbT,
    __hip_bfloat16* __restrict__ xb,
    const float* __restrict__ wq, const float* __restrict__ wk,
    const float* __restrict__ wv,
    __hip_bfloat16* __restrict__ wqkb, __hip_bfloat16* __restrict__ wvb,
    const float* __restrict__ gamma)
{
    int b = blockIdx.z, c0 = blockIdx.y * 64, n0 = blockIdx.x * 64;
    __shared__ float t[64][65];
    int tid = threadIdx.x;
    const bool do_cam = (gamma[0] != 0.0f);

    if (b == 0) {
        int wid = blockIdx.y * 64 + blockIdx.x;
        #pragma unroll
        for (int e = 0; e < 2; ++e) {
            int id = wid*320 + e*256 + tid;
            if (e*256 + tid < 320) {
                if (id < 64*256) {
                    float v = (id < 32*256) ? wq[id] : wk[id - 32*256];
                    wqkb[id] = __float2bfloat16(v);
                } else {
                    int j = id - 64*256;
                    wvb[j] = __float2bfloat16(wv[j]);
                }
            }
        }
    }

    int nn = tid & 63, ch = tid >> 6;
    const float* xp = x + (size_t)b*CH*NP + (size_t)c0*NP + n0;
    #pragma unroll
    for (int u = 0; u < 16; ++u) {
        float v = xp[(size_t)(ch + u*4)*NP + nn];
        t[ch + u*4][nn] = v;
        if (do_cam)
            xb[((size_t)b*CH + c0 + ch + u*4)*NP + n0 + nn] = __float2bfloat16(v);
    }
    __syncthreads();
    int n = tid >> 2, seg = tid & 3;
    union { __hip_bfloat16 h[16]; bf16x8 v[2]; } u16;
    #pragma unroll
    for (int u = 0; u < 16; ++u)
        u16.h[u] = __float2bfloat16(t[seg*16 + u][n]);
    __hip_bfloat16* dst = xbT + ((size_t)b*NP + n0 + n)*CH + c0 + seg*16;
    *(bf16x8*)dst = u16.v[0];
    *(bf16x8*)(dst + 8) = u16.v[1];
}

// ---- K1 (fused): qk (x<32) | v (32<=x<96) | energy (96<=x<112) -------------
__global__ __launch_bounds__(256) void mid_kernel(
    const __hip_bfloat16* __restrict__ xbT, const __hip_bfloat16* __restrict__ xb,
    const __hip_bfloat16* __restrict__ wqkb, const __hip_bfloat16* __restrict__ wvb,
    const float* __restrict__ bq, const float* __restrict__ bk,
    const float* __restrict__ bv,
    __hip_bfloat16* __restrict__ qt, __hip_bfloat16* __restrict__ kt,
    __hip_bfloat16* __restrict__ vb, float* __restrict__ E_part,
    const float* __restrict__ gamma)
{
    const int xrole = blockIdx.x, b = blockIdx.y;
    const int tid = threadIdx.x;
    const int w = tid >> 6, l = tid & 63, g = l >> 4, li = l & 15;

    __shared__ __align__(16) char smem[40960];

    if (xrole < 32) {
        const int n0 = xrole * 128;
        __hip_bfloat16* Ap = (__hip_bfloat16*)smem;
        __hip_bfloat16* Bp = (__hip_bfloat16*)(smem + 16384);

        f32x4 acc[2][4];
        #pragma unroll
        for (int mf = 0; mf < 2; ++mf)
            #pragma unroll
            for (int nf = 0; nf < 4; ++nf) acc[mf][nf] = (f32x4){0.f,0.f,0.f,0.f};

        const __hip_bfloat16* asrc = xbT + ((size_t)b*NP + n0)*CH;
        for (int kt4 = 0; kt4 < 4; ++kt4) {
            stage_panel64(asrc, CH, kt4*64, Ap, 128, w, l);
            stage_panel64(wqkb, CH, kt4*64, Bp, 64, w, l);
            __syncthreads();
            #pragma unroll
            for (int ks = 0; ks < 2; ++ks) {
                bf16x8 af[2], bf[4];
                #pragma unroll
                for (int mf = 0; mf < 2; ++mf) af[mf] = frag64(Ap, w*32 + mf*16 + li, ks*4 + g);
                #pragma unroll
                for (int nf = 0; nf < 4; ++nf) bf[nf] = frag64(Bp, nf*16 + li, ks*4 + g);
                #pragma unroll
                for (int mf = 0; mf < 2; ++mf)
                    #pragma unroll
                    for (int nf = 0; nf < 4; ++nf)
                        acc[mf][nf] = MFMA16(af[mf], bf[nf], acc[mf][nf]);
            }
            __syncthreads();
        }
        #pragma unroll
        for (int mf = 0; mf < 2; ++mf)
            #pragma unroll
            for (int nf = 0; nf < 4; ++nf)
                #pragma unroll
                for (int q = 0; q < 4; ++q) {
                    int n = n0 + w*32 + mf*16 + g*4 + q;
                    int o = nf*16 + li;
                    float bias = (o < 32) ? bq[o] : bk[o - 32];
                    float scl  = (o < 32) ? LOG2E : 1.0f;
                    __hip_bfloat16* dst = (o < 32) ? qt : kt;
                    dst[((size_t)b*NP + n)*C8 + (o & 31)] =
                        __float2bfloat16((acc[mf][nf][q] + bias) * scl);
                }
    } else if (xrole < 96) {
        const int n0 = (xrole - 32) * 64;
        __hip_bfloat16* Ap = (__hip_bfloat16*)smem;
        __hip_bfloat16* Bp = (__hip_bfloat16*)(smem + 32768);
        __hip_bfloat16* vt = (__hip_bfloat16*)smem;

        f32x4 acc[4][4];
        #pragma unroll
        for (int mf = 0; mf < 4; ++mf)
            #pragma unroll
            for (int nf = 0; nf < 4; ++nf) acc[mf][nf] = (f32x4){0.f,0.f,0.f,0.f};

        const __hip_bfloat16* bsrc = xbT + ((size_t)b*NP + n0)*CH;
        for (int kt4 = 0; kt4 < 4; ++kt4) {
            stage_panel64(wvb, CH, kt4*64, Ap, 256, w, l);
            stage_panel64(bsrc, CH, kt4*64, Bp, 64, w, l);
            __syncthreads();
            #pragma unroll
            for (int ks = 0; ks < 2; ++ks) {
                bf16x8 af[4], bf[4];
                #pragma unroll
                for (int mf = 0; mf < 4; ++mf) af[mf] = frag64(Ap, w*64 + mf*16 + li, ks*4 + g);
                #pragma unroll
                for (int nf = 0; nf < 4; ++nf) bf[nf] = frag64(Bp, nf*16 + li, ks*4 + g);
                #pragma unroll
                for (int mf = 0; mf < 4; ++mf)
                    #pragma unroll
                    for (int nf = 0; nf < 4; ++nf)
                        acc[mf][nf] = MFMA16(af[mf], bf[nf], acc[mf][nf]);
            }
            __syncthreads();
        }
        #pragma unroll
        for (int mf = 0; mf < 4; ++mf)
            #pragma unroll
            for (int nf = 0; nf < 4; ++nf)
                #pragma unroll
                for (int q = 0; q < 4; ++q) {
                    int c = w*64 + mf*16 + g*4 + q;
                    int n = nf*16 + li;
                    vt[c*72 + n] = __float2bfloat16(acc[mf][nf][q] + bv[c]);
                }
        __syncthreads();
        for (int S = tid; S < 2048; S += 256) {
            int c = S >> 3, s = S & 7;
            bf16x8 v = *(const bf16x8*)((const char*)vt + c*144 + s*16);
            *(bf16x8*)(vb + ((size_t)b*CH + c)*NP + n0 + s*8) = v;
        }
    } else {
        if (gamma[0] == 0.0f) return;   // CAM contributes gamma*cam == 0
        const int idx = xrole - 96;
        const int rh = idx & 3, kp = idx >> 2;
        __hip_bfloat16* P = (__hip_bfloat16*)smem;

        f32x4 acc[16];
        #pragma unroll
        for (int nf = 0; nf < 16; ++nf) acc[nf] = (f32x4){0.f,0.f,0.f,0.f};

        const __hip_bfloat16* xp = xb + (size_t)b*CH*NP;
        for (int kt4 = 0; kt4 < 16; ++kt4) {
            int k0 = kp*1024 + kt4*64;
            stage_panel64(xp, NP, k0, P, 256, w, l);
            __syncthreads();
            #pragma unroll
            for (int ks = 0; ks < 2; ++ks) {
                bf16x8 af = frag64(P, rh*64 + w*16 + li, ks*4 + g);
                #pragma unroll
                for (int nf = 0; nf < 16; ++nf) {
                    bf16x8 bf = frag64(P, nf*16 + li, ks*4 + g);
                    acc[nf] = MFMA16(af, bf, acc[nf]);
                }
            }
            __syncthreads();
        }
        #pragma unroll
        for (int nf = 0; nf < 16; ++nf)
            #pragma unroll
            for (int q = 0; q < 4; ++q) {
                int r = rh*64 + w*16 + g*4 + q;
                int c = nf*16 + li;
                E_part[(((size_t)b*4 + kp)*CH + r)*CH + c] = acc[nf][q];
            }
    }
}

// -------------------- K4: softmax over C (fused partial reduce) -> bf16 -----
__global__ __launch_bounds__(256) void cam_softmax(
    const float* __restrict__ E_part, __hip_bfloat16* __restrict__ attnb,
    const float* __restrict__ gamma)
{
    if (gamma[0] == 0.0f) return;       // CAM contributes gamma*cam == 0
    int b = blockIdx.y, r = blockIdx.x;
    int tid = threadIdx.x;
    int lane = tid & 63, wid = tid >> 6;
    const float* base = E_part + ((size_t)b*4*CH + r)*CH + tid;
    float e = base[0] + base[CH*CH] + base[2*CH*CH] + base[3*CH*CH];

    __shared__ float redm[4], reds[4];
    float m = e;
    #pragma unroll
    for (int off = 32; off >= 1; off >>= 1) m = fmaxf(m, __shfl_xor(m, off));
    if (lane == 0) redm[wid] = m;
    __syncthreads();
    m = fmaxf(fmaxf(redm[0], redm[1]), fmaxf(redm[2], redm[3]));

    float p = __expf(e - m);
    float s = p;
    #pragma unroll
    for (int off = 32; off >= 1; off >>= 1) s += __shfl_xor(s, off);
    if (lane == 0) reds[wid] = s;
    __syncthreads();
    s = reds[0] + reds[1] + reds[2] + reds[3];
    attnb[((size_t)b*CH + r)*CH + tid] = __float2bfloat16(p / s);
}

// ---- K6: PAM flash v16 — v15 pipelined loop; CAM epilogue only if gamma!=0 -
__global__ __launch_bounds__(256, 2) void pam_flash(
    const __hip_bfloat16* __restrict__ qg,   // [B][N][32] (pre-scaled)
    const __hip_bfloat16* __restrict__ kg,   // [B][N][32]
    const __hip_bfloat16* __restrict__ vg,   // [B][C][N]
    const __hip_bfloat16* __restrict__ attnb,// [B][C][C]
    const __hip_bfloat16* __restrict__ xbT,  // [B][N][C]
    const float* __restrict__ x,
    const float* __restrict__ gamma,
    float* __restrict__ out)
{
    const int bid = blockIdx.x;
    const int b   = bid & 7;                 // batch -> XCD pin (L2 residency)
    const int i0  = (bid >> 3) * 64;
    const int tid = threadIdx.x;
    const int w   = tid >> 6;
    const int l   = tid & 63;
    const int g   = l >> 4;
    const int li  = l & 15;

    __shared__ __align__(16) __hip_bfloat16 vs[256*64];     // 32KB, wave-private
    __shared__ __align__(16) __hip_bfloat16 ps[2][64*64];   // 16KB dbuf
    __shared__ float lsh[4][64];                            // 1KB

    // V staging geometry: slot S16 = w*512 + it*64 + l;
    // c = w*64 + it*8 + (l>>3); jb = (l&7)^(c&7) is constant across it.
    const int c0l = (w*512 + l) >> 3;
    const int jb  = (l & 7) ^ (c0l & 7);
    const char* vbase = (const char*)vg + ((size_t)(b*CH + c0l)*NP + jb*8)*2;

#define ISSUE_V(JT)                                                           \
    { _Pragma("unroll")                                                       \
      for (int it = 0; it < 8; ++it)                                          \
          async_copy16(vbase + (size_t)(JT)*128 + (size_t)it*(8*NP*2),        \
                       (char*)vs + w*8192 + it*1024); }

#define PS_WRITE(PSB, ST)                                                     \
    { _Pragma("unroll")                                                       \
      for (int t = 0; t < 4; ++t) {                                           \
          float p0 = EXP2(ST[t][0]);                                          \
          float p1 = EXP2(ST[t][1]);                                          \
          float p2 = EXP2(ST[t][2]);                                          \
          float p3 = EXP2(ST[t][3]);                                          \
          lacc[t] += (p0 + p1) + (p2 + p3);                                   \
          *(unsigned long long*)((PSB) + (t*16 + li)*128 +                    \
              (((2*w + (g >> 1)) ^ (li & 7)) << 4) + ((g & 1) << 3))          \
              = pack4bf(p0, p1, p2, p3);                                      \
      } }

#define PV_BLOCK(PSB)                                                         \
    { _Pragma("unroll")                                                       \
      for (int ks = 0; ks < 2; ++ks) {                                        \
          bf16x8 ap[4];                                                       \
          _Pragma("unroll")                                                   \
          for (int t = 0; t < 4; ++t)                                         \
              ap[t] = *(const bf16x8*)((PSB) + (t*16 + li)*128 +              \
                          (((ks*4 + g) ^ (li & 7)) << 4));                    \
          _Pragma("unroll")                                                   \
          for (int ct = 0; ct < 4; ++ct) {                                    \
              int c = w*64 + ct*16 + li;                                      \
              bf16x8 bv = *(const bf16x8*)((const char*)vs + c*128 +          \
                              (((ks*4 + g) ^ (c & 7)) << 4));                 \
              _Pragma("unroll")                                               \
              for (int t = 0; t < 4; ++t)                                     \
                  acc[t][ct] = MFMA16(ap[t], bv, acc[t][ct]);                 \
          }                                                                   \
      } }

    // Q frags direct from global
    const char* qbase = (const char*)(qg + ((size_t)b*NP + i0)*C8);
    bf16x8 qf[4];
    #pragma unroll
    for (int t = 0; t < 4; ++t)
        qf[t] = *(const bf16x8*)(qbase + (t*16 + li)*64 + g*16);

    // prologue issues (order pinned): K0, V0 x8, K1, K2
    const char* kptr = (const char*)(kg + (size_t)b*NP*C8) + (w*16 + li)*64 + g*16;
    bf16x8 k0 = *(const bf16x8*)(kptr);
    SBAR();
    ISSUE_V(0);
    SBAR();
    bf16x8 kcur  = *(const bf16x8*)(kptr + 4096);
    bf16x8 knext = *(const bf16x8*)(kptr + 2*4096);
    SBAR();

    f32x4 acc[4][4];
    #pragma unroll
    for (int t = 0; t < 4; ++t)
        #pragma unroll
        for (int ct = 0; ct < 4; ++ct)
            acc[t][ct] = (f32x4){0.f, 0.f, 0.f, 0.f};
    float lacc[4] = {0.f, 0.f, 0.f, 0.f};

    // ---- P(0): QK(0) + exp2 -> ps[0] ----
    {
        f32x4 st[4];
        #pragma unroll
        for (int t = 0; t < 4; ++t) {
            f32x4 z = (f32x4){0.f, 0.f, 0.f, 0.f};
            st[t] = MFMA16(k0, qf[t], z);
        }
        PS_WRITE((char*)ps, st);
    }
    asm volatile("s_waitcnt lgkmcnt(0)" ::: "memory");
    SBAR();
    __builtin_amdgcn_s_barrier();
    SBAR();

    // ---- pipelined main loop: phase = PV(jt) ∥ QK(jt+1) ----
    for (int jt = 0; jt < 63; ++jt) {
        const int cur = jt & 1;
        char* psc = (char*)ps + cur*8192;         // read: written last phase
        char* psn = (char*)ps + (cur ^ 1)*8192;   // write: read 2 phases ago

        asm volatile("s_waitcnt vmcnt(1)" ::: "memory");   // V(jt) landed
        SBAR();
        __builtin_amdgcn_s_setprio(1);
        // QK(jt+1) — issues first, completes under PV's MFMA stream
        f32x4 st[4];
        #pragma unroll
        for (int t = 0; t < 4; ++t) {
            f32x4 z = (f32x4){0.f, 0.f, 0.f, 0.f};
            st[t] = MFMA16(kcur, qf[t], z);
        }
        // PV(jt)
        PV_BLOCK(psc);
        __builtin_amdgcn_s_setprio(0);
        // exp2 tail on VALU (overlaps MFMA drain) -> ps[next]
        PS_WRITE(psn, st);
        SBAR();
        // V(jt+1) into same buffer: after all vs reads (program order)
        ISSUE_V(jt + 1);
        SBAR();
        kcur = knext;
        int kn3 = (jt + 3 < 64) ? (jt + 3) : 63;
        knext = *(const bf16x8*)(kptr + (size_t)kn3*4096);
        SBAR();
        asm volatile("s_waitcnt lgkmcnt(0)" ::: "memory");
        SBAR();
        __builtin_amdgcn_s_barrier();    // the ONLY barrier per iter
        SBAR();
    }

    // ---- drain: PV(63) from ps[1] ----
    {
        char* psc = (char*)ps + 8192;
        asm volatile("s_waitcnt vmcnt(1)" ::: "memory");
        SBAR();
        __builtin_amdgcn_s_setprio(1);
        PV_BLOCK(psc);
        __builtin_amdgcn_s_setprio(0);
    }

    // ---- reduce l across lane groups then waves ----
    #pragma unroll
    for (int t = 0; t < 4; ++t) {
        float v = lacc[t];
        v += __shfl_xor(v, 16);
        v += __shfl_xor(v, 32);
        lacc[t] = v;
    }
    if (g == 0) {
        #pragma unroll
        for (int t = 0; t < 4; ++t) lsh[w][t*16 + li] = lacc[t];
    }
    __syncthreads();   // also: all PV reads of vs/ps complete -> reusable

    float linv[4][4];
    #pragma unroll
    for (int t = 0; t < 4; ++t)
        #pragma unroll
        for (int r = 0; r < 4; ++r) {
            int il = t*16 + g*4 + r;
            linv[t][r] = 1.0f / (lsh[0][il] + lsh[1][il] + lsh[2][il] + lsh[3][il]);
        }

    // ---- CAM epilogue (only when gamma != 0): cacc = attn @ X ----
    const float g0 = gamma[0];
    f32x4 cacc[4][4];
    #pragma unroll
    for (int t = 0; t < 4; ++t)
        #pragma unroll
        for (int ct = 0; ct < 4; ++ct)
            cacc[t][ct] = (f32x4){0.f, 0.f, 0.f, 0.f};

    if (g0 != 0.0f) {
        __hip_bfloat16* Bpan = vs;                    // 256x64 attn rows (32KB)
        __hip_bfloat16* Apan = (__hip_bfloat16*)ps;   // 64x64 xbT rows (8KB)
        const __hip_bfloat16* csrc = attnb + (size_t)b*CH*CH;
        const __hip_bfloat16* nsrc = xbT + ((size_t)b*NP + i0)*CH;
        for (int kt4 = 0; kt4 < 4; ++kt4) {
            stage_panel64(csrc, CH, kt4*64, Bpan, 256, w, l);
            stage_panel64(nsrc, CH, kt4*64, Apan, 64, w, l);
            __syncthreads();
            #pragma unroll
            for (int ks = 0; ks < 2; ++ks) {
                bf16x8 af[4], bfv[4];
                #pragma unroll
                for (int t = 0; t < 4; ++t) af[t] = frag64(Apan, t*16 + li, ks*4 + g);
                #pragma unroll
                for (int ct = 0; ct < 4; ++ct)
                    bfv[ct] = frag64(Bpan, w*64 + ct*16 + li, ks*4 + g);
                #pragma unroll
                for (int t = 0; t < 4; ++t)
                    #pragma unroll
                    for (int ct = 0; ct < 4; ++ct)
                        cacc[t][ct] = MFMA16(af[t], bfv[ct], cacc[t][ct]);
            }
            __syncthreads();
        }
    }

    // ---- single fused write: out = gamma*cam + x + pam/l ----
    #pragma unroll
    for (int t = 0; t < 4; ++t) {
        #pragma unroll
        for (int ct = 0; ct < 4; ++ct) {
            int c = w*64 + ct*16 + li;
            size_t base = ((size_t)b*CH + c)*NP + i0 + t*16 + g*4;
            float4 xv = *(const float4*)(x + base);
            float4 o;
            o.x = g0*cacc[t][ct][0] + xv.x + acc[t][ct][0]*linv[t][0];
            o.y = g0*cacc[t][ct][1] + xv.y + acc[t][ct][1]*linv[t][1];
            o.z = g0*cacc[t][ct][2] + xv.z + acc[t][ct][2]*linv[t][2];
            o.w = g0*cacc[t][ct][3] + xv.w + acc[t][ct][3]*linv[t][3];
            *(float4*)(out + base) = o;
        }
    }
#undef ISSUE_V
#undef PS_WRITE
#undef PV_BLOCK
}

// ---------------------------------------------------------------------------
extern "C" void kernel_launch(void* const* d_in, const int* in_sizes, int n_in,
                              void* d_out, int out_size, void* d_ws, size_t ws_size,
                              hipStream_t stream)
{
    const float* x     = (const float*)d_in[0];
    const float* gamma = (const float*)d_in[1];
    const float* wq    = (const float*)d_in[2];
    const float* bq    = (const float*)d_in[3];
    const float* wk    = (const float*)d_in[4];
    const float* bk    = (const float*)d_in[5];
    const float* wv    = (const float*)d_in[6];
    const float* bv    = (const float*)d_in[7];
    float* out = (float*)d_out;

    char* ws = (char*)d_ws;
    __hip_bfloat16* xbT   = (__hip_bfloat16*)ws;                 ws += (size_t)BB*NP*CH*2;
    __hip_bfloat16* xb    = (__hip_bfloat16*)ws;                 ws += (size_t)BB*CH*NP*2;
    __hip_bfloat16* qtb   = (__hip_bfloat16*)ws;                 ws += (size_t)BB*NP*C8*2;
    __hip_bfloat16* ktb   = (__hip_bfloat16*)ws;                 ws += (size_t)BB*NP*C8*2;
    __hip_bfloat16* vbb   = (__hip_bfloat16*)ws;                 ws += (size_t)BB*CH*NP*2;
    __hip_bfloat16* wqkb  = (__hip_bfloat16*)ws;                 ws += 64*CH*2;
    __hip_bfloat16* wvb   = (__hip_bfloat16*)ws;                 ws += CH*CH*2;
    float*          Epart = (float*)ws;                          ws += (size_t)BB*4*CH*CH*4;
    __hip_bfloat16* attnb = (__hip_bfloat16*)ws;                 ws += (size_t)BB*CH*CH*2;

    convert_T  <<<dim3(64, 4, BB),  256, 0, stream>>>(x, xbT, xb, wq, wk, wv, wqkb, wvb, gamma);
    mid_kernel <<<dim3(112, BB),    256, 0, stream>>>(xbT, xb, wqkb, wvb, bq, bk, bv,
                                                      qtb, ktb, vbb, Epart, gamma);
    cam_softmax<<<dim3(CH, BB),     256, 0, stream>>>(Epart, attnb, gamma);
    pam_flash  <<<dim3(512),        256, 0, stream>>>(qtb, ktb, vbb, attnb, xbT,
                                                      x, gamma, out);
}

// Round 19
// 123.716 us; speedup vs baseline: 10.7462x; 1.0016x over previous
//
#include <hip/hip_runtime.h>
#include <hip/hip_bf16.h>

#define BB 8
#define CH 256
#define C8 32
#define NP 4096   // 64*64

typedef __attribute__((ext_vector_type(8))) short bf16x8;
typedef __attribute__((ext_vector_type(4))) float f32x4;

#define MFMA16(a, b, c) __builtin_amdgcn_mfma_f32_16x16x32_bf16(a, b, c, 0, 0, 0)
#define SBAR() __builtin_amdgcn_sched_barrier(0)

#if __has_builtin(__builtin_amdgcn_exp2f)
#define EXP2(x) __builtin_amdgcn_exp2f(x)
#else
#define EXP2(x) exp2f(x)
#endif

#define LOG2E 1.44269504088896340736f

__device__ __forceinline__ void async_copy16(const void* src, void* dst_lds) {
    __builtin_amdgcn_global_load_lds(
        (const __attribute__((address_space(1))) unsigned int*)src,
        (__attribute__((address_space(3))) unsigned int*)dst_lds, 16, 0, 0);
}

__device__ __forceinline__ unsigned long long pack4bf(float a, float b, float c, float d) {
    union { __hip_bfloat16 h[4]; unsigned long long u; } p;
    p.h[0] = __float2bfloat16(a);
    p.h[1] = __float2bfloat16(b);
    p.h[2] = __float2bfloat16(c);
    p.h[3] = __float2bfloat16(d);
    return p.u;
}

// Stage a [nrows][64] bf16 LDS panel (128B rows, XOR-swizzled: data k-chunk t
// of row r lives at slot t^(r&7)) from row-major bf16 global. 256-thread form.
__device__ __forceinline__ void stage_panel64(
    const __hip_bfloat16* __restrict__ src, int rowStride, int k0,
    __hip_bfloat16* lds, int nrows, int w, int l)
{
    const int nslots = nrows * 8;
    for (int S0 = w*64; S0 < nslots; S0 += 256) {
        int S = S0 + l;
        int r = S >> 3, s = S & 7;
        int jb = s ^ (r & 7);
        async_copy16(src + (size_t)r*rowStride + k0 + jb*8,
                     (char*)lds + (size_t)S0*16);
    }
}

__device__ __forceinline__ bf16x8 frag64(const __hip_bfloat16* lds, int r, int t) {
    return *(const bf16x8*)((const char*)lds + r*128 + ((t ^ (r & 7)) << 4));
}

// ------- K0: x -> xbT [B][N][C] bf16 + xb [B][C][N] bf16 (+ weights) --------
// xb is only consumed by the CAM energy path; skipped when gamma==0.
__global__ __launch_bounds__(256) void convert_T(
    const float* __restrict__ x, __hip_bfloat16* __restrict__ xbT,
    __hip_bfloat16* __restrict__ xb,
    const float* __restrict__ wq, const float* __restrict__ wk,
    const float* __restrict__ wv,
    __hip_bfloat16* __restrict__ wqkb, __hip_bfloat16* __restrict__ wvb,
    const float* __restrict__ gamma)
{
    int b = blockIdx.z, c0 = blockIdx.y * 64, n0 = blockIdx.x * 64;
    __shared__ float t[64][65];
    int tid = threadIdx.x;
    const bool do_cam = (gamma[0] != 0.0f);

    if (b == 0) {
        int wid = blockIdx.y * 64 + blockIdx.x;
        #pragma unroll
        for (int e = 0; e < 2; ++e) {
            int id = wid*320 + e*256 + tid;
            if (e*256 + tid < 320) {
                if (id < 64*256) {
                    float v = (id < 32*256) ? wq[id] : wk[id - 32*256];
                    wqkb[id] = __float2bfloat16(v);
                } else {
                    int j = id - 64*256;
                    wvb[j] = __float2bfloat16(wv[j]);
                }
            }
        }
    }

    int nn = tid & 63, ch = tid >> 6;
    const float* xp = x + (size_t)b*CH*NP + (size_t)c0*NP + n0;
    #pragma unroll
    for (int u = 0; u < 16; ++u) {
        float v = xp[(size_t)(ch + u*4)*NP + nn];
        t[ch + u*4][nn] = v;
        if (do_cam)
            xb[((size_t)b*CH + c0 + ch + u*4)*NP + n0 + nn] = __float2bfloat16(v);
    }
    __syncthreads();
    int n = tid >> 2, seg = tid & 3;
    union { __hip_bfloat16 h[16]; bf16x8 v[2]; } u16;
    #pragma unroll
    for (int u = 0; u < 16; ++u)
        u16.h[u] = __float2bfloat16(t[seg*16 + u][n]);
    __hip_bfloat16* dst = xbT + ((size_t)b*NP + n0 + n)*CH + c0 + seg*16;
    *(bf16x8*)dst = u16.v[0];
    *(bf16x8*)(dst + 8) = u16.v[1];
}

// ---- K1 (fused): qk (x<32) | v (32<=x<96) | energy (96<=x<112) -------------
__global__ __launch_bounds__(256) void mid_kernel(
    const __hip_bfloat16* __restrict__ xbT, const __hip_bfloat16* __restrict__ xb,
    const __hip_bfloat16* __restrict__ wqkb, const __hip_bfloat16* __restrict__ wvb,
    const float* __restrict__ bq, const float* __restrict__ bk,
    const float* __restrict__ bv,
    __hip_bfloat16* __restrict__ qt, __hip_bfloat16* __restrict__ kt,
    __hip_bfloat16* __restrict__ vb, float* __restrict__ E_part,
    const float* __restrict__ gamma)
{
    const int xrole = blockIdx.x, b = blockIdx.y;
    const int tid = threadIdx.x;
    const int w = tid >> 6, l = tid & 63, g = l >> 4, li = l & 15;

    __shared__ __align__(16) char smem[40960];

    if (xrole < 32) {
        const int n0 = xrole * 128;
        __hip_bfloat16* Ap = (__hip_bfloat16*)smem;
        __hip_bfloat16* Bp = (__hip_bfloat16*)(smem + 16384);

        f32x4 acc[2][4];
        #pragma unroll
        for (int mf = 0; mf < 2; ++mf)
            #pragma unroll
            for (int nf = 0; nf < 4; ++nf) acc[mf][nf] = (f32x4){0.f,0.f,0.f,0.f};

        const __hip_bfloat16* asrc = xbT + ((size_t)b*NP + n0)*CH;
        for (int kt4 = 0; kt4 < 4; ++kt4) {
            stage_panel64(asrc, CH, kt4*64, Ap, 128, w, l);
            stage_panel64(wqkb, CH, kt4*64, Bp, 64, w, l);
            __syncthreads();
            #pragma unroll
            for (int ks = 0; ks < 2; ++ks) {
                bf16x8 af[2], bf[4];
                #pragma unroll
                for (int mf = 0; mf < 2; ++mf) af[mf] = frag64(Ap, w*32 + mf*16 + li, ks*4 + g);
                #pragma unroll
                for (int nf = 0; nf < 4; ++nf) bf[nf] = frag64(Bp, nf*16 + li, ks*4 + g);
                #pragma unroll
                for (int mf = 0; mf < 2; ++mf)
                    #pragma unroll
                    for (int nf = 0; nf < 4; ++nf)
                        acc[mf][nf] = MFMA16(af[mf], bf[nf], acc[mf][nf]);
            }
            __syncthreads();
        }
        // ---- coalesced epilogue: stage [128][66] in LDS, copy out b128 ----
        __hip_bfloat16* vt = (__hip_bfloat16*)smem;   // 128*66*2 = 16.9KB
        #pragma unroll
        for (int mf = 0; mf < 2; ++mf)
            #pragma unroll
            for (int nf = 0; nf < 4; ++nf)
                #pragma unroll
                for (int q = 0; q < 4; ++q) {
                    int nl = w*32 + mf*16 + g*4 + q;
                    int o  = nf*16 + li;
                    float bias = (o < 32) ? bq[o] : bk[o - 32];
                    float scl  = (o < 32) ? LOG2E : 1.0f;
                    vt[nl*66 + o] = __float2bfloat16((acc[mf][nf][q] + bias) * scl);
                }
        __syncthreads();
        for (int S = tid; S < 1024; S += 256) {
            int nl = S >> 3, chk = S & 7;
            bf16x8 v = *(const bf16x8*)(vt + nl*66 + chk*8);
            __hip_bfloat16* dst = (chk < 4) ? qt : kt;
            dst[((size_t)b*NP + n0 + nl)*C8 + (chk & 3)*8 + 0] = ((__hip_bfloat16*)&v)[0];
            *(bf16x8*)(dst + ((size_t)b*NP + n0 + nl)*C8 + (chk & 3)*8) = v;
        }
    } else if (xrole < 96) {
        const int n0 = (xrole - 32) * 64;
        __hip_bfloat16* Ap = (__hip_bfloat16*)smem;
        __hip_bfloat16* Bp = (__hip_bfloat16*)(smem + 32768);
        __hip_bfloat16* vt = (__hip_bfloat16*)smem;

        f32x4 acc[4][4];
        #pragma unroll
        for (int mf = 0; mf < 4; ++mf)
            #pragma unroll
            for (int nf = 0; nf < 4; ++nf) acc[mf][nf] = (f32x4){0.f,0.f,0.f,0.f};

        const __hip_bfloat16* bsrc = xbT + ((size_t)b*NP + n0)*CH;
        for (int kt4 = 0; kt4 < 4; ++kt4) {
            stage_panel64(wvb, CH, kt4*64, Ap, 256, w, l);
            stage_panel64(bsrc, CH, kt4*64, Bp, 64, w, l);
            __syncthreads();
            #pragma unroll
            for (int ks = 0; ks < 2; ++ks) {
                bf16x8 af[4], bf[4];
                #pragma unroll
                for (int mf = 0; mf < 4; ++mf) af[mf] = frag64(Ap, w*64 + mf*16 + li, ks*4 + g);
                #pragma unroll
                for (int nf = 0; nf < 4; ++nf) bf[nf] = frag64(Bp, nf*16 + li, ks*4 + g);
                #pragma unroll
                for (int mf = 0; mf < 4; ++mf)
                    #pragma unroll
                    for (int nf = 0; nf < 4; ++nf)
                        acc[mf][nf] = MFMA16(af[mf], bf[nf], acc[mf][nf]);
            }
            __syncthreads();
        }
        #pragma unroll
        for (int mf = 0; mf < 4; ++mf)
            #pragma unroll
            for (int nf = 0; nf < 4; ++nf)
                #pragma unroll
                for (int q = 0; q < 4; ++q) {
                    int c = w*64 + mf*16 + g*4 + q;
                    int n = nf*16 + li;
                    vt[c*72 + n] = __float2bfloat16(acc[mf][nf][q] + bv[c]);
                }
        __syncthreads();
        for (int S = tid; S < 2048; S += 256) {
            int c = S >> 3, s = S & 7;
            bf16x8 v = *(const bf16x8*)((const char*)vt + c*144 + s*16);
            *(bf16x8*)(vb + ((size_t)b*CH + c)*NP + n0 + s*8) = v;
        }
    } else {
        if (gamma[0] == 0.0f) return;   // CAM contributes gamma*cam == 0
        const int idx = xrole - 96;
        const int rh = idx & 3, kp = idx >> 2;
        __hip_bfloat16* P = (__hip_bfloat16*)smem;

        f32x4 acc[16];
        #pragma unroll
        for (int nf = 0; nf < 16; ++nf) acc[nf] = (f32x4){0.f,0.f,0.f,0.f};

        const __hip_bfloat16* xp = xb + (size_t)b*CH*NP;
        for (int kt4 = 0; kt4 < 16; ++kt4) {
            int k0 = kp*1024 + kt4*64;
            stage_panel64(xp, NP, k0, P, 256, w, l);
            __syncthreads();
            #pragma unroll
            for (int ks = 0; ks < 2; ++ks) {
                bf16x8 af = frag64(P, rh*64 + w*16 + li, ks*4 + g);
                #pragma unroll
                for (int nf = 0; nf < 16; ++nf) {
                    bf16x8 bf = frag64(P, nf*16 + li, ks*4 + g);
                    acc[nf] = MFMA16(af, bf, acc[nf]);
                }
            }
            __syncthreads();
        }
        #pragma unroll
        for (int nf = 0; nf < 16; ++nf)
            #pragma unroll
            for (int q = 0; q < 4; ++q) {
                int r = rh*64 + w*16 + g*4 + q;
                int c = nf*16 + li;
                E_part[(((size_t)b*4 + kp)*CH + r)*CH + c] = acc[nf][q];
            }
    }
}

// -------------------- K4: softmax over C (fused partial reduce) -> bf16 -----
__global__ __launch_bounds__(256) void cam_softmax(
    const float* __restrict__ E_part, __hip_bfloat16* __restrict__ attnb,
    const float* __restrict__ gamma)
{
    if (gamma[0] == 0.0f) return;       // CAM contributes gamma*cam == 0
    int b = blockIdx.y, r = blockIdx.x;
    int tid = threadIdx.x;
    int lane = tid & 63, wid = tid >> 6;
    const float* base = E_part + ((size_t)b*4*CH + r)*CH + tid;
    float e = base[0] + base[CH*CH] + base[2*CH*CH] + base[3*CH*CH];

    __shared__ float redm[4], reds[4];
    float m = e;
    #pragma unroll
    for (int off = 32; off >= 1; off >>= 1) m = fmaxf(m, __shfl_xor(m, off));
    if (lane == 0) redm[wid] = m;
    __syncthreads();
    m = fmaxf(fmaxf(redm[0], redm[1]), fmaxf(redm[2], redm[3]));

    float p = __expf(e - m);
    float s = p;
    #pragma unroll
    for (int off = 32; off >= 1; off >>= 1) s += __shfl_xor(s, off);
    if (lane == 0) reds[wid] = s;
    __syncthreads();
    s = reds[0] + reds[1] + reds[2] + reds[3];
    attnb[((size_t)b*CH + r)*CH + tid] = __float2bfloat16(p / s);
}

// ---- K6: PAM flash v19 — v16 loop, loop-invariant LDS offsets hoisted ------
__global__ __launch_bounds__(256, 2) void pam_flash(
    const __hip_bfloat16* __restrict__ qg,   // [B][N][32] (pre-scaled)
    const __hip_bfloat16* __restrict__ kg,   // [B][N][32]
    const __hip_bfloat16* __restrict__ vg,   // [B][C][N]
    const __hip_bfloat16* __restrict__ attnb,// [B][C][C]
    const __hip_bfloat16* __restrict__ xbT,  // [B][N][C]
    const float* __restrict__ x,
    const float* __restrict__ gamma,
    float* __restrict__ out)
{
    const int bid = blockIdx.x;
    const int b   = bid & 7;                 // batch -> XCD pin (L2 residency)
    const int i0  = (bid >> 3) * 64;
    const int tid = threadIdx.x;
    const int w   = tid >> 6;
    const int l   = tid & 63;
    const int g   = l >> 4;
    const int li  = l & 15;

    __shared__ __align__(16) __hip_bfloat16 vs[256*64];     // 32KB, wave-private
    __shared__ __align__(16) __hip_bfloat16 ps[2][64*64];   // 16KB dbuf
    __shared__ float lsh[4][64];                            // 1KB

    // V staging geometry: slot S16 = w*512 + it*64 + l;
    // c = w*64 + it*8 + (l>>3); jb = (l&7)^(c&7) is constant across it.
    const int c0l = (w*512 + l) >> 3;
    const int jb  = (l & 7) ^ (c0l & 7);
    const char* vbase = (const char*)vg + ((size_t)(b*CH + c0l)*NP + jb*8)*2;

    // ---- hoisted loop-invariant addresses (VGPR headroom: 128 -> ~190) ----
    const char* vit[8];
    char* vdst[8];
    #pragma unroll
    for (int it = 0; it < 8; ++it) {
        vit[it]  = vbase + (size_t)it*(8*NP*2);
        vdst[it] = (char*)vs + w*8192 + it*1024;
    }
    int psw[4];
    #pragma unroll
    for (int t = 0; t < 4; ++t)
        psw[t] = (t*16 + li)*128 + (((2*w + (g >> 1)) ^ (li & 7)) << 4) + ((g & 1) << 3);
    int apo[2][4], bvo[2][4];
    #pragma unroll
    for (int ks = 0; ks < 2; ++ks) {
        #pragma unroll
        for (int t = 0; t < 4; ++t)
            apo[ks][t] = (t*16 + li)*128 + (((ks*4 + g) ^ (li & 7)) << 4);
        #pragma unroll
        for (int ct = 0; ct < 4; ++ct) {
            int c = w*64 + ct*16 + li;
            bvo[ks][ct] = c*128 + (((ks*4 + g) ^ (c & 7)) << 4);
        }
    }

#define ISSUE_V(JT)                                                           \
    { _Pragma("unroll")                                                       \
      for (int it = 0; it < 8; ++it)                                          \
          async_copy16(vit[it] + (size_t)(JT)*128, vdst[it]); }

#define PS_WRITE(PSB, ST)                                                     \
    { _Pragma("unroll")                                                       \
      for (int t = 0; t < 4; ++t) {                                           \
          float p0 = EXP2(ST[t][0]);                                          \
          float p1 = EXP2(ST[t][1]);                                          \
          float p2 = EXP2(ST[t][2]);                                          \
          float p3 = EXP2(ST[t][3]);                                          \
          lacc[t] += (p0 + p1) + (p2 + p3);                                   \
          *(unsigned long long*)((PSB) + psw[t]) = pack4bf(p0, p1, p2, p3);   \
      } }

#define PV_BLOCK(PSB)                                                         \
    { _Pragma("unroll")                                                       \
      for (int ks = 0; ks < 2; ++ks) {                                        \
          bf16x8 ap[4];                                                       \
          _Pragma("unroll")                                                   \
          for (int t = 0; t < 4; ++t)                                         \
              ap[t] = *(const bf16x8*)((PSB) + apo[ks][t]);                   \
          _Pragma("unroll")                                                   \
          for (int ct = 0; ct < 4; ++ct) {                                    \
              bf16x8 bv = *(const bf16x8*)((const char*)vs + bvo[ks][ct]);    \
              _Pragma("unroll")                                               \
              for (int t = 0; t < 4; ++t)                                     \
                  acc[t][ct] = MFMA16(ap[t], bv, acc[t][ct]);                 \
          }                                                                   \
      } }

    // Q frags direct from global
    const char* qbase = (const char*)(qg + ((size_t)b*NP + i0)*C8);
    bf16x8 qf[4];
    #pragma unroll
    for (int t = 0; t < 4; ++t)
        qf[t] = *(const bf16x8*)(qbase + (t*16 + li)*64 + g*16);

    // prologue issues (order pinned): K0, V0 x8, K1, K2
    const char* kptr = (const char*)(kg + (size_t)b*NP*C8) + (w*16 + li)*64 + g*16;
    bf16x8 k0 = *(const bf16x8*)(kptr);
    SBAR();
    ISSUE_V(0);
    SBAR();
    bf16x8 kcur  = *(const bf16x8*)(kptr + 4096);
    bf16x8 knext = *(const bf16x8*)(kptr + 2*4096);
    SBAR();

    f32x4 acc[4][4];
    #pragma unroll
    for (int t = 0; t < 4; ++t)
        #pragma unroll
        for (int ct = 0; ct < 4; ++ct)
            acc[t][ct] = (f32x4){0.f, 0.f, 0.f, 0.f};
    float lacc[4] = {0.f, 0.f, 0.f, 0.f};

    // ---- P(0): QK(0) + exp2 -> ps[0] ----
    {
        f32x4 st[4];
        #pragma unroll
        for (int t = 0; t < 4; ++t) {
            f32x4 z = (f32x4){0.f, 0.f, 0.f, 0.f};
            st[t] = MFMA16(k0, qf[t], z);
        }
        PS_WRITE((char*)ps, st);
    }
    asm volatile("s_waitcnt lgkmcnt(0)" ::: "memory");
    SBAR();
    __builtin_amdgcn_s_barrier();
    SBAR();

    // ---- pipelined main loop: phase = PV(jt) ∥ QK(jt+1) ----
    for (int jt = 0; jt < 63; ++jt) {
        const int cur = jt & 1;
        char* psc = (char*)ps + cur*8192;         // read: written last phase
        char* psn = (char*)ps + (cur ^ 1)*8192;   // write: read 2 phases ago

        asm volatile("s_waitcnt vmcnt(1)" ::: "memory");   // V(jt) landed
        SBAR();
        __builtin_amdgcn_s_setprio(1);
        // QK(jt+1) — issues first, completes under PV's MFMA stream
        f32x4 st[4];
        #pragma unroll
        for (int t = 0; t < 4; ++t) {
            f32x4 z = (f32x4){0.f, 0.f, 0.f, 0.f};
            st[t] = MFMA16(kcur, qf[t], z);
        }
        // PV(jt)
        PV_BLOCK(psc);
        __builtin_amdgcn_s_setprio(0);
        // exp2 tail on VALU (overlaps MFMA drain) -> ps[next]
        PS_WRITE(psn, st);
        SBAR();
        // V(jt+1) into same buffer: after all vs reads (program order)
        ISSUE_V(jt + 1);
        SBAR();
        kcur = knext;
        int kn3 = (jt + 3 < 64) ? (jt + 3) : 63;
        knext = *(const bf16x8*)(kptr + (size_t)kn3*4096);
        SBAR();
        asm volatile("s_waitcnt lgkmcnt(0)" ::: "memory");
        SBAR();
        __builtin_amdgcn_s_barrier();    // the ONLY barrier per iter
        SBAR();
    }

    // ---- drain: PV(63) from ps[1] ----
    {
        char* psc = (char*)ps + 8192;
        asm volatile("s_waitcnt vmcnt(1)" ::: "memory");
        SBAR();
        __builtin_amdgcn_s_setprio(1);
        PV_BLOCK(psc);
        __builtin_amdgcn_s_setprio(0);
    }

    // ---- reduce l across lane groups then waves ----
    #pragma unroll
    for (int t = 0; t < 4; ++t) {
        float v = lacc[t];
        v += __shfl_xor(v, 16);
        v += __shfl_xor(v, 32);
        lacc[t] = v;
    }
    if (g == 0) {
        #pragma unroll
        for (int t = 0; t < 4; ++t) lsh[w][t*16 + li] = lacc[t];
    }
    __syncthreads();   // also: all PV reads of vs/ps complete -> reusable

    float linv[4][4];
    #pragma unroll
    for (int t = 0; t < 4; ++t)
        #pragma unroll
        for (int r = 0; r < 4; ++r) {
            int il = t*16 + g*4 + r;
            linv[t][r] = 1.0f / (lsh[0][il] + lsh[1][il] + lsh[2][il] + lsh[3][il]);
        }

    // ---- CAM epilogue (only when gamma != 0): cacc = attn @ X ----
    const float g0 = gamma[0];
    f32x4 cacc[4][4];
    #pragma unroll
    for (int t = 0; t < 4; ++t)
        #pragma unroll
        for (int ct = 0; ct < 4; ++ct)
            cacc[t][ct] = (f32x4){0.f, 0.f, 0.f, 0.f};

    if (g0 != 0.0f) {
        __hip_bfloat16* Bpan = vs;                    // 256x64 attn rows (32KB)
        __hip_bfloat16* Apan = (__hip_bfloat16*)ps;   // 64x64 xbT rows (8KB)
        const __hip_bfloat16* csrc = attnb + (size_t)b*CH*CH;
        const __hip_bfloat16* nsrc = xbT + ((size_t)b*NP + i0)*CH;
        for (int kt4 = 0; kt4 < 4; ++kt4) {
            stage_panel64(csrc, CH, kt4*64, Bpan, 256, w, l);
            stage_panel64(nsrc, CH, kt4*64, Apan, 64, w, l);
            __syncthreads();
            #pragma unroll
            for (int ks = 0; ks < 2; ++ks) {
                bf16x8 af[4], bfv[4];
                #pragma unroll
                for (int t = 0; t < 4; ++t) af[t] = frag64(Apan, t*16 + li, ks*4 + g);
                #pragma unroll
                for (int ct = 0; ct < 4; ++ct)
                    bfv[ct] = frag64(Bpan, w*64 + ct*16 + li, ks*4 + g);
                #pragma unroll
                for (int t = 0; t < 4; ++t)
                    #pragma unroll
                    for (int ct = 0; ct < 4; ++ct)
                        cacc[t][ct] = MFMA16(af[t], bfv[ct], cacc[t][ct]);
            }
            __syncthreads();
        }
    }

    // ---- single fused write: out = gamma*cam + x + pam/l ----
    #pragma unroll
    for (int t = 0; t < 4; ++t) {
        #pragma unroll
        for (int ct = 0; ct < 4; ++ct) {
            int c = w*64 + ct*16 + li;
            size_t base = ((size_t)b*CH + c)*NP + i0 + t*16 + g*4;
            float4 xv = *(const float4*)(x + base);
            float4 o;
            o.x = g0*cacc[t][ct][0] + xv.x + acc[t][ct][0]*linv[t][0];
            o.y = g0*cacc[t][ct][1] + xv.y + acc[t][ct][1]*linv[t][1];
            o.z = g0*cacc[t][ct][2] + xv.z + acc[t][ct][2]*linv[t][2];
            o.w = g0*cacc[t][ct][3] + xv.w + acc[t][ct][3]*linv[t][3];
            *(float4*)(out + base) = o;
        }
    }
#undef ISSUE_V
#undef PS_WRITE
#undef PV_BLOCK
}

// ---------------------------------------------------------------------------
extern "C" void kernel_launch(void* const* d_in, const int* in_sizes, int n_in,
                              void* d_out, int out_size, void* d_ws, size_t ws_size,
                              hipStream_t stream)
{
    const float* x     = (const float*)d_in[0];
    const float* gamma = (const float*)d_in[1];
    const float* wq    = (const float*)d_in[2];
    const float* bq    = (const float*)d_in[3];
    const float* wk    = (const float*)d_in[4];
    const float* bk    = (const float*)d_in[5];
    const float* wv    = (const float*)d_in[6];
    const float* bv    = (const float*)d_in[7];
    float* out = (float*)d_out;

    char* ws = (char*)d_ws;
    __hip_bfloat16* xbT   = (__hip_bfloat16*)ws;                 ws += (size_t)BB*NP*CH*2;
    __hip_bfloat16* xb    = (__hip_bfloat16*)ws;                 ws += (size_t)BB*CH*NP*2;
    __hip_bfloat16* qtb   = (__hip_bfloat16*)ws;                 ws += (size_t)BB*NP*C8*2;
    __hip_bfloat16* ktb   = (__hip_bfloat16*)ws;                 ws += (size_t)BB*NP*C8*2;
    __hip_bfloat16* vbb   = (__hip_bfloat16*)ws;                 ws += (size_t)BB*CH*NP*2;
    __hip_bfloat16* wqkb  = (__hip_bfloat16*)ws;                 ws += 64*CH*2;
    __hip_bfloat16* wvb   = (__hip_bfloat16*)ws;                 ws += CH*CH*2;
    float*          Epart = (float*)ws;                          ws += (size_t)BB*4*CH*CH*4;
    __hip_bfloat16* attnb = (__hip_bfloat16*)ws;                 ws += (size_t)BB*CH*CH*2;

    convert_T  <<<dim3(64, 4, BB),  256, 0, stream>>>(x, xbT, xb, wq, wk, wv, wqkb, wvb, gamma);
    mid_kernel <<<dim3(112, BB),    256, 0, stream>>>(xbT, xb, wqkb, wvb, bq, bk, bv,
                                                      qtb, ktb, vbb, Epart, gamma);
    cam_softmax<<<dim3(CH, BB),     256, 0, stream>>>(Epart, attnb, gamma);
    pam_flash  <<<dim3(512),        256, 0, stream>>>(qtb, ktb, vbb, attnb, xbT,
                                                      x, gamma, out);
}